// Round 1
// baseline (665.276 us; speedup 1.0000x reference)
//
#include <hip/hip_runtime.h>
#include <hip/hip_bf16.h>
#include <math.h>

#define BB 8
#define NN 4096
#define KNN 20
#define CH 64
#define SAMPLES (BB*NN*KNN)   /* 655360 */
#define EPSF 1e-5f
#define SLOPE 0.2f
#define MCOPY 32              /* mstats copies to spread atomic contention */

typedef float f32x4 __attribute__((ext_vector_type(4)));
typedef short bf16x8 __attribute__((ext_vector_type(8)));

/* decode order-preserving uint back to float */
__device__ __forceinline__ float key_decode(unsigned e) {
    return __uint_as_float((e & 0x80000000u) ? (e ^ 0x80000000u) : ~e);
}

/* ---------------- K0: per-batch: build pts4 + bitonic sort by x + zero stats --- */
__global__ __launch_bounds__(1024) void sort_kernel(const float* __restrict__ x,
        float4* __restrict__ pts4, float4* __restrict__ sp4, int* __restrict__ sidx,
        int* __restrict__ rankArr, double* __restrict__ zreg) {
#pragma clang fp contract(off)
    __shared__ unsigned long long S[NN];                     /* 32 KB */
    const int tid = threadIdx.x;
    const int b = blockIdx.x;
    if (b == 0 && tid < 992) zreg[tid] = 0.0;     /* mstats(864d) + stats2f(128d) */
    const float* xb = x + (size_t)b * 3 * NN;
    for (int i = tid; i < NN; i += 1024) {
        float mx = xb[i], my = xb[NN + i], mz = xb[2*NN + i];
        float sq = mx*mx; sq += my*my; sq += mz*mz;          /* ref summation order */
        pts4[(b << 12) + i] = make_float4(-2.0f*mx, -2.0f*my, -2.0f*mz, sq);
        unsigned uu = __float_as_uint(mx);
        unsigned e = uu ^ (((unsigned)((int)uu >> 31)) | 0x80000000u);
        S[i] = ((unsigned long long)e << 32) | (unsigned)i;
    }
    __syncthreads();
    for (int k = 2; k <= NN; k <<= 1) {
        for (int j = k >> 1; j > 0; j >>= 1) {
#pragma unroll
            for (int tt = 0; tt < 2; ++tt) {
                int t = tid + tt*1024;            /* 2048 pairs */
                int i = ((t & ~(j - 1)) << 1) | (t & (j - 1));
                int h = i | j;
                unsigned long long a = S[i], c = S[h];
                bool up = ((i & k) == 0);
                if ((a > c) == up) { S[i] = c; S[h] = a; }
            }
            __syncthreads();
        }
    }
    for (int s = tid; s < NN; s += 1024) {
        int oi = (int)(unsigned)(S[s] & 0xFFFFFFFFu);
        float mx = xb[oi], my = xb[NN + oi], mz = xb[2*NN + oi];  /* recompute: no RAW */
        float sq = mx*mx; sq += my*my; sq += mz*mz;
        sp4[(b << 12) + s] = make_float4(-2.0f*mx, -2.0f*my, -2.0f*mz, sq);
        sidx[(b << 12) + s] = oi;
        rankArr[(b << 12) + oi] = s;
    }
}

/* ---------------- K1: exact KNN — TRANSPOSED: one lane = one query. ------------
   A wave owns 64 consecutive sorted ranks. Candidate chunks (64 points) are
   staged in LDS and broadcast to all lanes (uniform ds_read_b128); each lane
   filters against its own threshold (3 fmaf + cmp per candidate serving 64
   query-candidate pairs per instruction). Survivors append to a per-lane LDS
   buffer ([entry][lane] layout: stride-8B across lanes, conflict-free); rare
   wave-synchronized flushes merge into a per-lane sorted top-20 incumbent
   list. Selection semantics identical to the previous sweep: same fmaf filter
   + margin M, same exact-d ref-parenthesization, same (enc(d)<<32)|idx key. */

#define BCAP 80   /* per-lane buffer entries; trigger<=16 + 64/chunk = 80 max */

__device__ __forceinline__ void lane_flush(unsigned long long* BUF,
        unsigned long long* INC, const int lane, int& cnt, int& m,
        float& kthd, const float sqn, float& M, float& thr) {
    for (int j = 0; j < cnt; ++j) {               /* divergent trip counts OK */
        unsigned long long key = BUF[(j << 6) + lane];
        if (m < KNN) {
            int i = m - 1;
            while (i >= 0 && INC[(i << 6) + lane] > key) {
                INC[((i + 1) << 6) + lane] = INC[(i << 6) + lane]; --i;
            }
            INC[((i + 1) << 6) + lane] = key; ++m;
        } else if (key < INC[((KNN - 1) << 6) + lane]) {
            int i = KNN - 2;
            while (i >= 0 && INC[(i << 6) + lane] > key) {
                INC[((i + 1) << 6) + lane] = INC[(i << 6) + lane]; --i;
            }
            INC[((i + 1) << 6) + lane] = key;
        }
    }
    cnt = 0;
    if (m == KNN) {
        kthd = key_decode((unsigned)(INC[((KNN - 1) << 6) + lane] >> 32));
        M = 1e-3f*(fabsf(kthd) + fabsf(sqn) + 1.0f);
        thr = (kthd - sqn) + M;
    }
}

__device__ __forceinline__ void eval_chunk(const float4* ch, const int* sic,
        unsigned long long* BUF, const int lane, const float qx, const float qy,
        const float qz, const float sqn, const float thr, int& cnt) {
#pragma clang fp contract(off)
#pragma unroll 8
    for (int t = 0; t < 64; ++t) {
        const float4 P = ch[t];                   /* uniform addr -> broadcast */
        const float sc = fmaf(P.x, qx, fmaf(P.y, qy, fmaf(P.z, qz, P.w)));
        const bool push = sc <= thr;
        if (__any(push)) {
            const float mx = -0.5f*P.x, my = -0.5f*P.y, mz = -0.5f*P.z;
            float inner = qx*mx; inner += qy*my; inner += qz*mz;
            const float d = (sqn - 2.0f*inner) + P.w;   /* ref parenthesization */
            unsigned uu = __float_as_uint(d);
            unsigned e = uu ^ (((unsigned)((int)uu >> 31)) | 0x80000000u);
            unsigned long long key = ((unsigned long long)e << 32) | (unsigned)sic[t];
            if (push) { BUF[(cnt << 6) + lane] = key; ++cnt; }
        }
    }
}

__global__ __launch_bounds__(64) void knn_kernel(const float4* __restrict__ pts4,
        const float4* __restrict__ sp4, const int* __restrict__ sidx,
        int* __restrict__ idx_out, double* __restrict__ mstats) {
#pragma clang fp contract(off)
    __shared__ float4 CHK[2][64];                            /* 2 KB  */
    __shared__ int    SIc[2][64];                            /* 0.5 KB */
    __shared__ unsigned long long BUF[BCAP*64];              /* 40 KB */
    __shared__ unsigned long long INC[KNN*64];               /* 10 KB */

    const int lane = threadIdx.x;                 /* 64-thread block = 1 wave */
    const int Q0 = blockIdx.x << 6;               /* global sorted rank base  */
    const int b  = Q0 >> 12;
    const int r0 = Q0 & (NN - 1);                 /* batch-local rank base    */
    const float4* sb = sp4 + ((size_t)b << 12);
    const int*    si = sidx + ((size_t)b << 12);

    /* lane's own query IS element r0+lane of the initial chunk */
    const float4 R0 = sb[r0 + lane];
    const int    Ri0 = si[r0 + lane];
    const float qx = -0.5f*R0.x, qy = -0.5f*R0.y, qz = -0.5f*R0.z;
    const float sqn = R0.w;

    int lo = r0, hi = r0 + 64;
    bool dl = (lo == 0), dr = (hi == NN);

    /* stage initial chunk (always full, always pushes: thr = +inf) */
    CHK[0][lane] = R0; SIc[0][lane] = Ri0;
    __builtin_amdgcn_wave_barrier();

    /* prefetch both side chunks before the initial eval (overlap) */
    float4 RL, RR; int RiL = 0, RiR = 0;
    int stL = 0, enR = NN;
    if (!dl) {
        stL = lo - 64; if (stL < 0) stL = 0;
        int ii = stL + lane; int ia = ii < lo ? ii : lo - 1;
        RL = sb[ia]; RiL = si[ia];
    }
    if (!dr) {
        enR = hi + 64; if (enR > NN) enR = NN;
        int ii = hi + lane; int ia = ii < NN - 1 ? ii : NN - 1;
        RR = sb[ia]; RiR = si[ia];
    }

    float kthd = INFINITY, M = INFINITY, thr = INFINITY;
    int cnt = 0, m = 0;

    eval_chunk(&CHK[0][0], &SIc[0][0], BUF, lane, qx, qy, qz, sqn, thr, cnt);

    while (!dl || !dr) {
        if (!dl) {
            /* prune vs nearest point of the prefetched chunk: x[lo-1] */
            const float xl = -0.5f * __shfl(RL.x, lo - 1 - stL);
            const float dx = qx - xl;
            if (__all(dx*dx > kthd + M)) dl = true;
            else {
                const bool v = (stL + lane) < lo;
                __builtin_amdgcn_wave_barrier();
                CHK[0][lane] = v ? RL : make_float4(0.f, 0.f, 0.f, INFINITY);
                SIc[0][lane] = v ? RiL : 0;       /* sentinel never pushes */
                __builtin_amdgcn_wave_barrier();
                const int lo2 = stL;
                const bool dl2 = (lo2 == 0);
                int stL2 = lo2 - 64; if (stL2 < 0) stL2 = 0;
                if (!dl2) {                       /* next prefetch in flight */
                    int ii = stL2 + lane; int ia = ii < lo2 ? ii : lo2 - 1;
                    RL = sb[ia]; RiL = si[ia];
                }
                if (__any(cnt > 16))
                    lane_flush(BUF, INC, lane, cnt, m, kthd, sqn, M, thr);
                eval_chunk(&CHK[0][0], &SIc[0][0], BUF, lane, qx, qy, qz, sqn, thr, cnt);
                lo = lo2; stL = stL2; dl = dl2;
            }
        }
        if (!dr) {
            const float xr = -0.5f * __shfl(RR.x, 0);
            const float dx = xr - qx;
            if (__all(dx*dx > kthd + M)) dr = true;
            else {
                const bool v = (hi + lane) < enR;
                __builtin_amdgcn_wave_barrier();
                CHK[1][lane] = v ? RR : make_float4(0.f, 0.f, 0.f, INFINITY);
                SIc[1][lane] = v ? RiR : 0;
                __builtin_amdgcn_wave_barrier();
                const int hi2 = enR;
                const bool dr2 = (hi2 == NN);
                int enR2 = hi2 + 64; if (enR2 > NN) enR2 = NN;
                if (!dr2) {
                    int ii = hi2 + lane; int ia = ii < NN - 1 ? ii : NN - 1;
                    RR = sb[ia]; RiR = si[ia];
                }
                if (__any(cnt > 16))
                    lane_flush(BUF, INC, lane, cnt, m, kthd, sqn, M, thr);
                eval_chunk(&CHK[1][0], &SIc[1][0], BUF, lane, qx, qy, qz, sqn, thr, cnt);
                hi = hi2; enR = enR2; dr = dr2;
            }
        }
    }
    lane_flush(BUF, INC, lane, cnt, m, kthd, sqn, M, thr);

    /* transpose top-20 through LDS (reuse BUF) for coalesced idx_out writes */
    unsigned* TB = (unsigned*)BUF;
#pragma unroll
    for (int j = 0; j < KNN; ++j)
        TB[lane*21 + j] = (unsigned)(INC[(j << 6) + lane] & 0xFFFFFFFFull);
    __builtin_amdgcn_wave_barrier();
    int* iout = idx_out + (size_t)Q0 * KNN;
#pragma unroll
    for (int u = 0; u < KNN; ++u) {
        int g = (u << 6) + lane;                  /* 1280 contiguous ints */
        iout[g] = (int)TB[(g / KNN)*21 + (g % KNN)];
    }

    /* moments epilogue: each lane sums over its own 20 neighbors */
    const float4* pb = pts4 + ((size_t)b << 12);
    float nx=0.f, ny=0.f, nz=0.f, xx=0.f, xy=0.f, xz=0.f, yy=0.f, yz=0.f, zz=0.f;
#pragma unroll
    for (int j = 0; j < KNN; ++j) {
        int nb = (int)(INC[(j << 6) + lane] & 0xFFFFFFFFull);
        float4 pn = pb[nb];
        float ax = -0.5f*pn.x, ay = -0.5f*pn.y, az = -0.5f*pn.z;
        nx += ax; ny += ay; nz += az;
        xx += ax*ax; xy += ax*ay; xz += ax*az;
        yy += ay*ay; yz += ay*az; zz += az*az;
    }
    double* msd = &mstats[(blockIdx.x & (MCOPY-1))*27];
#define RED27(v, i) { float r_ = (v); \
    r_ += __shfl_xor(r_, 1);  r_ += __shfl_xor(r_, 2);  r_ += __shfl_xor(r_, 4); \
    r_ += __shfl_xor(r_, 8);  r_ += __shfl_xor(r_, 16); r_ += __shfl_xor(r_, 32); \
    if (lane == 0) atomicAdd(&msd[i], (double)r_); }
    RED27(nx, 0) RED27(ny, 1) RED27(nz, 2)
    RED27(qx, 3) RED27(qy, 4) RED27(qz, 5)
    RED27(xx, 6) RED27(xy, 7) RED27(xz, 8)
    RED27(yy, 9) RED27(yz, 10) RED27(zz, 11)
    RED27(nx*qx, 12) RED27(nx*qy, 13) RED27(nx*qz, 14)
    RED27(ny*qx, 15) RED27(ny*qy, 16) RED27(ny*qz, 17)
    RED27(nz*qx, 18) RED27(nz*qy, 19) RED27(nz*qz, 20)
    RED27(qx*qx, 21) RED27(qx*qy, 22) RED27(qx*qz, 23)
    RED27(qy*qy, 24) RED27(qy*qz, 25) RED27(qz*qz, 26)
#undef RED27
}

/* split fp32 -> bf16 hi (truncate) + bf16 lo (truncated remainder) */
__device__ __forceinline__ void bsplit(float g, short& hi, short& lo) {
    unsigned bits = __float_as_uint(g);
    unsigned hbits = bits & 0xFFFF0000u;
    float rem = g - __uint_as_float(hbits);
    hi = (short)(bits >> 16);
    lo = (short)(__float_as_uint(rem) >> 16);
}

/* ---------------- K5: main pass — shared-leftover-tile split-bf16 MFMA --------- */
__global__ __launch_bounds__(256) void main_kernel(const int* __restrict__ idxb,
        const int* __restrict__ rankArr, const float4* __restrict__ pts4,
        const double* __restrict__ ms, const float* __restrict__ W1,
        const float* __restrict__ gamma1, const float* __restrict__ beta1,
        const float* __restrict__ W2,
        float* __restrict__ maxbuf, float* __restrict__ stats2f) {
    __shared__ __align__(16) short Thi[4][32*72];
    __shared__ __align__(16) short Tlo[4][32*72];
    __shared__ float chs[128];
    __shared__ float ab1s[128];
    __shared__ double msd[27];
    const int tid = threadIdx.x;
    const int lane = tid & 63;
    const int wv = __builtin_amdgcn_readfirstlane(tid >> 6);
    const int l15 = lane & 15;
    const int quad = lane >> 4;
    if (tid < 128) chs[tid] = 0.f;
    if (tid < 27) {                                /* sum the 32 mstats copies */
        double t = 0.0;
        for (int c = 0; c < MCOPY; ++c) t += ms[c*27 + tid];
        msd[tid] = t;
    }
    __syncthreads();
    if (tid < 64) {                                /* inline fin1m (bn1 affine) */
        int c = tid;
        double wu[3], wvv[3];
#pragma unroll
        for (int i = 0; i < 3; ++i) {
            wu[i] = (double)W1[c*6 + i];
            wvv[i] = (double)W1[c*6 + 3 + i] - wu[i];
        }
        const double S = (double)SAMPLES;
        double mean = (wu[0]*msd[0] + wu[1]*msd[1] + wu[2]*msd[2]
                     + 20.0*(wvv[0]*msd[3] + wvv[1]*msd[4] + wvv[2]*msd[5])) / S;
        double qM1 = wu[0]*wu[0]*msd[6] + wu[1]*wu[1]*msd[9] + wu[2]*wu[2]*msd[11]
                   + 2.0*(wu[0]*wu[1]*msd[7] + wu[0]*wu[2]*msd[8] + wu[1]*wu[2]*msd[10]);
        double cross = 0.0;
#pragma unroll
        for (int i = 0; i < 3; ++i)
#pragma unroll
            for (int j = 0; j < 3; ++j)
                cross += wu[i] * msd[12 + i*3 + j] * wvv[j];
        double qpp = wvv[0]*wvv[0]*msd[21] + wvv[1]*wvv[1]*msd[24] + wvv[2]*wvv[2]*msd[26]
                   + 2.0*(wvv[0]*wvv[1]*msd[22] + wvv[0]*wvv[2]*msd[23] + wvv[1]*wvv[2]*msd[25]);
        double e2 = (qM1 + 2.0*cross + 20.0*qpp) / S;
        double var = e2 - mean*mean;
        float a = (float)((double)gamma1[c] / sqrt(var + (double)EPSF));
        ab1s[c] = a;
        ab1s[64 + c] = beta1[c] - a * (float)mean;
    }
    __syncthreads();

    bf16x8 whi[8], wlo[8];
#pragma unroll
    for (int t = 0; t < 4; ++t)
#pragma unroll
    for (int f = 0; f < 2; ++f) {
        const int o = 16*t + l15;
        const int c0 = 32*f + quad*8;
        const float4* wr = (const float4*)(W2 + o*64 + c0);
        float4 w0 = wr[0], w1 = wr[1];
        float vals[8] = {w0.x,w0.y,w0.z,w0.w,w1.x,w1.y,w1.z,w1.w};
        bf16x8 h, l;
#pragma unroll
        for (int j = 0; j < 8; ++j) { short hj, lj; bsplit(vals[j], hj, lj); h[j]=hj; l[j]=lj; }
        whi[t*2+f] = h; wlo[t*2+f] = l;
    }

    const float w10 = W1[lane*6+0], w11 = W1[lane*6+1], w12 = W1[lane*6+2];
    const float w13 = W1[lane*6+3], w14 = W1[lane*6+4], w15 = W1[lane*6+5];
    const float a1 = ab1s[lane], b1 = ab1s[64 + lane];
    float ssum[4] = {0.f,0.f,0.f,0.f}, ssq[4] = {0.f,0.f,0.f,0.f};
    float lm[4][4];                                /* deferred tile1 max [point][t] */
    short* thi = &Thi[wv][0];
    short* tlo = &Tlo[wv][0];

    const int pt0 = (blockIdx.x * 4 + wv) * 4;
    const int b = pt0 >> 12;
    const float4* pb = pts4 + ((size_t)b << 12);
    const int* rnk = rankArr + ((size_t)b << 12);

    for (int p = 0; p < 4; ++p) {
        const int pt = pt0 + p;
        const float4 pc = pb[pt & (NN - 1)];
        const float X = -0.5f*pc.x, Y = -0.5f*pc.y, Z = -0.5f*pc.z;
        const float vc = (w13 - w10)*X + (w14 - w11)*Y + (w15 - w12)*Z;
        const int srow = rnk[pt & (NN - 1)];       /* uniform scalar lookup */
        const int* irow = idxb + ((size_t)((b << 12) + srow)) * KNN;
#pragma unroll
        for (int k = 0; k < KNN; ++k) {
            float4 pn = pb[irow[k]];
            float nx = -0.5f*pn.x, ny = -0.5f*pn.y, nz = -0.5f*pn.z;
            float uc = w10*nx + w11*ny + w12*nz;
            float g = a1 * (uc + vc) + b1;
            g = fmaxf(g, SLOPE * g);
            short hj, lj; bsplit(g, hj, lj);
            const int row = (k < 16) ? k : (16 + p*4 + (k - 16));
            thi[row*72 + lane] = hj;
            tlo[row*72 + lane] = lj;
        }
        __builtin_amdgcn_wave_barrier();

        bf16x8 ah1[2], al1[2];
#pragma unroll
        for (int f = 0; f < 2; ++f) {
            const int co = 32*f + quad*8;
            ah1[f] = *(const bf16x8*)&thi[l15*72 + co];
            al1[f] = *(const bf16x8*)&tlo[l15*72 + co];
        }

        f32x4 acc1[4];
#pragma unroll
        for (int t = 0; t < 4; ++t) acc1[t] = (f32x4)0.f;
#pragma unroll
        for (int t = 0; t < 4; ++t) {
#pragma unroll
            for (int f = 0; f < 2; ++f) {
                acc1[t] = __builtin_amdgcn_mfma_f32_16x16x32_bf16(ah1[f], whi[t*2+f], acc1[t], 0,0,0);
                acc1[t] = __builtin_amdgcn_mfma_f32_16x16x32_bf16(al1[f], whi[t*2+f], acc1[t], 0,0,0);
                acc1[t] = __builtin_amdgcn_mfma_f32_16x16x32_bf16(ah1[f], wlo[t*2+f], acc1[t], 0,0,0);
            }
        }
        __builtin_amdgcn_wave_barrier();           /* tile1 reads done before next p */

        /* tile1 epilogue: reduce over rows k=0..15 (quads), defer the write */
#pragma unroll
        for (int t = 0; t < 4; ++t) {
            float m1 = fmaxf(fmaxf(acc1[t][0], acc1[t][1]), fmaxf(acc1[t][2], acc1[t][3]));
            float s1 = acc1[t][0] + acc1[t][1] + acc1[t][2] + acc1[t][3];
            float q1 = acc1[t][0]*acc1[t][0] + acc1[t][1]*acc1[t][1]
                     + acc1[t][2]*acc1[t][2] + acc1[t][3]*acc1[t][3];
            m1 = fmaxf(m1, __shfl_xor(m1, 16)); m1 = fmaxf(m1, __shfl_xor(m1, 32));
            s1 += __shfl_xor(s1, 16); s1 += __shfl_xor(s1, 32);
            q1 += __shfl_xor(q1, 16); q1 += __shfl_xor(q1, 32);
            lm[p][t] = m1;
            ssum[t] += s1; ssq[t] += q1;
        }
    }

    /* combined leftover tile: rows = p*4+(k-16), read once, 24 MFMA */
    {
        bf16x8 ah2[2], al2[2];
#pragma unroll
        for (int f = 0; f < 2; ++f) {
            const int co = 32*f + quad*8;
            ah2[f] = *(const bf16x8*)&thi[(16 + l15)*72 + co];
            al2[f] = *(const bf16x8*)&tlo[(16 + l15)*72 + co];
        }
        f32x4 accC[4];
#pragma unroll
        for (int t = 0; t < 4; ++t) accC[t] = (f32x4)0.f;
#pragma unroll
        for (int t = 0; t < 4; ++t) {
#pragma unroll
            for (int f = 0; f < 2; ++f) {
                accC[t] = __builtin_amdgcn_mfma_f32_16x16x32_bf16(ah2[f], whi[t*2+f], accC[t], 0,0,0);
                accC[t] = __builtin_amdgcn_mfma_f32_16x16x32_bf16(al2[f], whi[t*2+f], accC[t], 0,0,0);
                accC[t] = __builtin_amdgcn_mfma_f32_16x16x32_bf16(ah2[f], wlo[t*2+f], accC[t], 0,0,0);
            }
        }
        /* C row = quad*4+reg -> point = quad, k = 16+reg. */
#pragma unroll
        for (int t = 0; t < 4; ++t) {
            float cm = fmaxf(fmaxf(accC[t][0], accC[t][1]), fmaxf(accC[t][2], accC[t][3]));
            float cs = accC[t][0] + accC[t][1] + accC[t][2] + accC[t][3];
            float cq = accC[t][0]*accC[t][0] + accC[t][1]*accC[t][1]
                     + accC[t][2]*accC[t][2] + accC[t][3]*accC[t][3];
            float lmq = (quad == 0) ? lm[0][t] : (quad == 1) ? lm[1][t]
                      : (quad == 2) ? lm[2][t] : lm[3][t];
            maxbuf[((size_t)(pt0 + quad) << 6) + 16*t + l15] = fmaxf(lmq, cm);
            cs += __shfl_xor(cs, 16); cs += __shfl_xor(cs, 32);
            cq += __shfl_xor(cq, 16); cq += __shfl_xor(cq, 32);
            ssum[t] += cs; ssq[t] += cq;
        }
    }

    if (quad == 0) {
#pragma unroll
        for (int t = 0; t < 4; ++t) {
            atomicAdd(&chs[16*t + l15], ssum[t]);
            atomicAdd(&chs[64 + 16*t + l15], ssq[t]);
        }
    }
    __syncthreads();
    if (tid < 128)
        atomicAdd(&stats2f[(blockIdx.x & 1)*128 + tid], chs[tid]);
}

/* ---------------- K7: epilogue — fin2 inlined; transpose + bn2 + lrelu --------- */
__global__ __launch_bounds__(256) void out_kernel(const float* __restrict__ maxbuf,
        const float* __restrict__ s2f, const float* __restrict__ gamma2,
        const float* __restrict__ beta2, float* __restrict__ out) {
    __shared__ float t[64][65];
    __shared__ float ab2s[128];
    const int tid = threadIdx.x;
    if (tid < 64) {                                /* inline fin2 */
        int o = tid;
        double sum = (double)s2f[o] + (double)s2f[128 + o];
        double sq  = (double)s2f[64 + o] + (double)s2f[192 + o];
        double cnt = (double)SAMPLES;
        double mean = sum / cnt;
        double var  = sq / cnt - mean*mean;
        float a = (float)((double)gamma2[o] / sqrt(var + (double)EPSF));
        ab2s[o] = a;
        ab2s[64 + o] = beta2[o] - a * (float)mean;
    }
    const int b = blockIdx.x >> 6;
    const int n0 = (blockIdx.x & 63) << 6;
#pragma unroll
    for (int i = 0; i < 16; ++i) {
        int r = (tid >> 6) + i*4;
        int c = tid & 63;
        t[r][c] = maxbuf[(((size_t)((b << 12) + n0 + r)) << 6) + c];
    }
    __syncthreads();
#pragma unroll
    for (int i = 0; i < 16; ++i) {
        int o = (tid >> 6) + i*4;
        int nn = tid & 63;
        float a = ab2s[o], bb = ab2s[64 + o];
        float h = a * t[nn][o] + bb;
        out[(((size_t)(b*64 + o)) << 12) + n0 + nn] = h >= 0.f ? h : SLOPE*h;
    }
}

extern "C" void kernel_launch(void* const* d_in, const int* in_sizes, int n_in,
                              void* d_out, int out_size, void* d_ws, size_t ws_size,
                              hipStream_t stream) {
    const float* x      = (const float*)d_in[0];
    const float* W1     = (const float*)d_in[1];
    const float* gamma1 = (const float*)d_in[2];
    const float* beta1  = (const float*)d_in[3];
    const float* W2     = (const float*)d_in[4];
    const float* gamma2 = (const float*)d_in[5];
    const float* beta2  = (const float*)d_in[6];
    float* out = (float*)d_out;

    char* ws = (char*)d_ws;
    int*    idxb    = (int*)   (ws + 0);           /* 2,621,440 B (sorted order) */
    float4* pts4    = (float4*)(ws + 2621440);     /* 512 KB */
    float4* sp4     = (float4*)(ws + 3145728);     /* 512 KB sorted pts */
    int*    sidx    = (int*)   (ws + 3670016);     /* 128 KB sorted->orig */
    int*    rankArr = (int*)   (ws + 3801088);     /* 128 KB orig->sorted */
    float*  maxbuf  = (float*) (ws + 19398656);    /* 8,388,608 B, (b,n,o) */
    double* mstats  = (double*)(ws + 27787264);    /* 32x27 doubles = 6912 B */
    float*  stats2f = (float*) (ws + 27794176);    /* 2x128 floats = 1024 B */
    double* zreg    = (double*)(ws + 27787264);    /* zero region: 992 doubles */

    sort_kernel <<<8, 1024, 0, stream>>>(x, pts4, sp4, sidx, rankArr, zreg);
    knn_kernel  <<<512, 64, 0, stream>>>(pts4, sp4, sidx, idxb, mstats);
    main_kernel <<<2048, 256, 0, stream>>>(idxb, rankArr, pts4, mstats, W1, gamma1,
                                           beta1, W2, maxbuf, stats2f);
    out_kernel  <<<512, 256, 0, stream>>>(maxbuf, stats2f, gamma2, beta2, out);
}

// Round 2
// 518.505 us; speedup vs baseline: 1.2831x; 1.2831x over previous
//
#include <hip/hip_runtime.h>
#include <hip/hip_bf16.h>
#include <math.h>

#define BB 8
#define NN 4096
#define KNN 20
#define CH 64
#define SAMPLES (BB*NN*KNN)   /* 655360 */
#define EPSF 1e-5f
#define SLOPE 0.2f
#define MCOPY 32              /* mstats copies to spread atomic contention */

typedef float f32x4 __attribute__((ext_vector_type(4)));
typedef short bf16x8 __attribute__((ext_vector_type(8)));

/* decode order-preserving uint back to float */
__device__ __forceinline__ float key_decode(unsigned e) {
    return __uint_as_float((e & 0x80000000u) ? (e ^ 0x80000000u) : ~e);
}

/* ---------------- K0: per-batch: build pts4 + bitonic sort by x + zero stats --- */
__global__ __launch_bounds__(1024) void sort_kernel(const float* __restrict__ x,
        float4* __restrict__ pts4, float4* __restrict__ sp4, int* __restrict__ sidx,
        int* __restrict__ rankArr, double* __restrict__ zreg) {
#pragma clang fp contract(off)
    __shared__ unsigned long long S[NN];                     /* 32 KB */
    const int tid = threadIdx.x;
    const int b = blockIdx.x;
    if (b == 0 && tid < 992) zreg[tid] = 0.0;     /* mstats(864d) + stats2f(128d) */
    const float* xb = x + (size_t)b * 3 * NN;
    for (int i = tid; i < NN; i += 1024) {
        float mx = xb[i], my = xb[NN + i], mz = xb[2*NN + i];
        float sq = mx*mx; sq += my*my; sq += mz*mz;          /* ref summation order */
        pts4[(b << 12) + i] = make_float4(-2.0f*mx, -2.0f*my, -2.0f*mz, sq);
        unsigned uu = __float_as_uint(mx);
        unsigned e = uu ^ (((unsigned)((int)uu >> 31)) | 0x80000000u);
        S[i] = ((unsigned long long)e << 32) | (unsigned)i;
    }
    __syncthreads();
    for (int k = 2; k <= NN; k <<= 1) {
        for (int j = k >> 1; j > 0; j >>= 1) {
#pragma unroll
            for (int tt = 0; tt < 2; ++tt) {
                int t = tid + tt*1024;            /* 2048 pairs */
                int i = ((t & ~(j - 1)) << 1) | (t & (j - 1));
                int h = i | j;
                unsigned long long a = S[i], c = S[h];
                bool up = ((i & k) == 0);
                if ((a > c) == up) { S[i] = c; S[h] = a; }
            }
            __syncthreads();
        }
    }
    for (int s = tid; s < NN; s += 1024) {
        int oi = (int)(unsigned)(S[s] & 0xFFFFFFFFu);
        float mx = xb[oi], my = xb[NN + oi], mz = xb[2*NN + oi];  /* recompute: no RAW */
        float sq = mx*mx; sq += my*my; sq += mz*mz;
        sp4[(b << 12) + s] = make_float4(-2.0f*mx, -2.0f*my, -2.0f*mz, sq);
        sidx[(b << 12) + s] = oi;
        rankArr[(b << 12) + oi] = s;
    }
}

/* ---------------- K1: exact KNN — transposed (1 lane = 1 query), register-hot.
   Candidate chunks live in prefetch registers and are broadcast with
   v_readlane (compile-time lane index): zero memory ops in the inner filter.
   Per-lane top-20 is a sorted 40-VGPR array updated by a branchless insert
   network (all positions computed from OLD values: no dependent chain).
   LDS holds only the append-only push buffer ([entry][lane], stride-8B:
   conflict-free), flushed once per chunk with next-entry prefetch.
   Selection semantics identical to the verified sweep: same fmaf filter +
   margin M, same exact-d ref-parenthesization, same (enc(d)<<32)|idx keys. */

#define BCAP 64   /* max pushes between flushes = one chunk */

__device__ __forceinline__ float rlf(float v, int l) {
    return __uint_as_float((unsigned)__builtin_amdgcn_readlane((int)__float_as_uint(v), l));
}

/* branchless sorted insert of key into ascending k[0..19] (drops old k[19]) */
__device__ __forceinline__ void insert20(unsigned long long (&k)[20],
                                         const unsigned long long key) {
    bool c[20];
#pragma unroll
    for (int i = 0; i < 20; ++i) c[i] = key < k[i];
#pragma unroll
    for (int i = 19; i >= 1; --i)
        k[i] = c[i-1] ? k[i-1] : (c[i] ? key : k[i]);
    k[0] = c[0] ? key : k[0];
}

__device__ __forceinline__ void flush20(unsigned long long* BUF, const int lane,
        int& cnt, unsigned long long (&k)[20], float& kthd, const float sqn,
        float& M, float& thr) {
#pragma clang fp contract(off)
    unsigned long long key = BUF[lane];           /* j=0 prefetched */
    int j = 0;
    while (__any(j < cnt)) {
        unsigned long long keyn = BUF[((j + 1) << 6) + lane];  /* hide LDS lat */
        const bool acc = (j < cnt) && (key < k[19]);
        if (__any(acc)) { if (acc) insert20(k, key); }
        key = keyn; ++j;
    }
    cnt = 0;
    const unsigned e19 = (unsigned)(k[19] >> 32);
    const float kd = key_decode(e19);
    kthd = (e19 != 0xFFFFFFFFu) ? kd : INFINITY;  /* guard: list not yet full */
    M = 1e-3f*(fabsf(kthd) + fabsf(sqn) + 1.0f);
    thr = (kthd - sqn) + M;
}

/* evaluate candidates [T0, T0+16) of the register chunk C/Ci (slot = lane) */
template<int T0>
__device__ __forceinline__ void eval16(const float4 C, const int Ci,
        unsigned long long* BUF, const int lane, const float qx, const float qy,
        const float qz, const float sqn, const float thr, int& cnt) {
#pragma clang fp contract(off)
#pragma unroll
    for (int u = 0; u < 16; ++u) {
        const int t = T0 + u;
        const float px = rlf(C.x, t);
        const float py = rlf(C.y, t);
        const float pz = rlf(C.z, t);
        const float pw = rlf(C.w, t);
        const float sc = fmaf(px, qx, fmaf(py, qy, fmaf(pz, qz, pw)));
        const bool push = sc <= thr;
        if (__any(push)) {
            const int pidx = __builtin_amdgcn_readlane(Ci, t);
            const float mx = -0.5f*px, my = -0.5f*py, mz = -0.5f*pz;
            float inner = qx*mx; inner += qy*my; inner += qz*mz;
            const float d = (sqn - 2.0f*inner) + pw;    /* ref parenthesization */
            const unsigned uu = __float_as_uint(d);
            const unsigned e = uu ^ (((unsigned)((int)uu >> 31)) | 0x80000000u);
            const unsigned long long keyv =
                ((unsigned long long)e << 32) | (unsigned)pidx;
            if (push) { BUF[(cnt << 6) + lane] = keyv; ++cnt; }
        }
    }
}

__global__ __launch_bounds__(64) void knn_kernel(const float4* __restrict__ pts4,
        const float4* __restrict__ sp4, const int* __restrict__ sidx,
        int* __restrict__ idx_out, double* __restrict__ mstats) {
#pragma clang fp contract(off)
    __shared__ unsigned long long BUF[(BCAP+1)*64];          /* 33.3 KB (+pad row) */

    const int lane = threadIdx.x;                 /* 64-thread block = 1 wave */
    const int Q0 = blockIdx.x << 6;               /* global sorted rank base  */
    const int b  = Q0 >> 12;
    const int r0 = Q0 & (NN - 1);                 /* batch-local, multiple of 64 */
    const float4* sb = sp4 + ((size_t)b << 12);
    const int*    si = sidx + ((size_t)b << 12);

    /* lane's own query IS slot `lane` of the initial chunk */
    const float4 R0 = sb[r0 + lane];
    const int    Ri0 = si[r0 + lane];
    const float qx = -0.5f*R0.x, qy = -0.5f*R0.y, qz = -0.5f*R0.z;
    const float sqn = R0.w;

    unsigned long long k[20];
#pragma unroll
    for (int j = 0; j < 20; ++j) k[j] = ~0ull;

    int lo = r0, hi = r0 + 64;                    /* always multiples of 64 ->  */
    bool dl = (lo == 0), dr = (hi == NN);         /* chunks always full, no clamps */
    float4 RL = R0, RR = R0; int RiL = 0, RiR = 0;
    if (!dl) { RL = sb[lo - 64 + lane]; RiL = si[lo - 64 + lane]; }
    if (!dr) { RR = sb[hi + lane];      RiR = si[hi + lane]; }

    float kthd = INFINITY, M = INFINITY, thr = INFINITY;
    int cnt = 0;

    /* prefill: 4x (eval16 + flush) so the threshold tightens mid-chunk */
    eval16<0> (R0, Ri0, BUF, lane, qx,qy,qz,sqn, thr, cnt);
    flush20(BUF, lane, cnt, k, kthd, sqn, M, thr);
    eval16<16>(R0, Ri0, BUF, lane, qx,qy,qz,sqn, thr, cnt);
    flush20(BUF, lane, cnt, k, kthd, sqn, M, thr);
    eval16<32>(R0, Ri0, BUF, lane, qx,qy,qz,sqn, thr, cnt);
    flush20(BUF, lane, cnt, k, kthd, sqn, M, thr);
    eval16<48>(R0, Ri0, BUF, lane, qx,qy,qz,sqn, thr, cnt);
    flush20(BUF, lane, cnt, k, kthd, sqn, M, thr);

    while (!dl || !dr) {
        if (!dl) {
            /* nearest point of prefetched left chunk = its last slot (x asc) */
            const float xl = rlf(RL.x, 63);
            const float dxl = qx - (-0.5f*xl);
            if (__all(dxl*dxl > kthd + M)) dl = true;
            else {
                const float4 CL = RL; const int CiL = RiL;
                const int lo2 = lo - 64;
                if (lo2 > 0) { RL = sb[lo2 - 64 + lane]; RiL = si[lo2 - 64 + lane]; }
                eval16<0> (CL, CiL, BUF, lane, qx,qy,qz,sqn, thr, cnt);
                eval16<16>(CL, CiL, BUF, lane, qx,qy,qz,sqn, thr, cnt);
                eval16<32>(CL, CiL, BUF, lane, qx,qy,qz,sqn, thr, cnt);
                eval16<48>(CL, CiL, BUF, lane, qx,qy,qz,sqn, thr, cnt);
                flush20(BUF, lane, cnt, k, kthd, sqn, M, thr);
                lo = lo2; dl = (lo == 0);
            }
        }
        if (!dr) {
            const float xr = rlf(RR.x, 0);
            const float dxr = (-0.5f*xr) - qx;
            if (__all(dxr*dxr > kthd + M)) dr = true;
            else {
                const float4 CR = RR; const int CiR = RiR;
                const int hi2 = hi + 64;
                if (hi2 < NN) { RR = sb[hi2 + lane]; RiR = si[hi2 + lane]; }
                eval16<0> (CR, CiR, BUF, lane, qx,qy,qz,sqn, thr, cnt);
                eval16<16>(CR, CiR, BUF, lane, qx,qy,qz,sqn, thr, cnt);
                eval16<32>(CR, CiR, BUF, lane, qx,qy,qz,sqn, thr, cnt);
                eval16<48>(CR, CiR, BUF, lane, qx,qy,qz,sqn, thr, cnt);
                flush20(BUF, lane, cnt, k, kthd, sqn, M, thr);
                hi = hi2; dr = (hi == NN);
            }
        }
    }

    /* transpose top-20 through LDS (reuse BUF) for coalesced idx_out writes */
    unsigned* TB = (unsigned*)BUF;
#pragma unroll
    for (int j = 0; j < KNN; ++j)
        TB[lane*21 + j] = (unsigned)(k[j] & 0xFFFFFFFFull);
    __builtin_amdgcn_wave_barrier();
    int* iout = idx_out + (size_t)Q0 * KNN;
#pragma unroll
    for (int u = 0; u < KNN; ++u) {
        int g = (u << 6) + lane;                  /* 1280 contiguous ints */
        iout[g] = (int)TB[(g / KNN)*21 + (g % KNN)];
    }

    /* moments epilogue: each lane sums over its own 20 neighbors */
    const float4* pb = pts4 + ((size_t)b << 12);
    float nx=0.f, ny=0.f, nz=0.f, xx=0.f, xy=0.f, xz=0.f, yy=0.f, yz=0.f, zz=0.f;
#pragma unroll
    for (int j = 0; j < KNN; ++j) {
        int nb = (int)(unsigned)(k[j] & 0xFFFFFFFFull);
        float4 pn = pb[nb];
        float ax = -0.5f*pn.x, ay = -0.5f*pn.y, az = -0.5f*pn.z;
        nx += ax; ny += ay; nz += az;
        xx += ax*ax; xy += ax*ay; xz += ax*az;
        yy += ay*ay; yz += ay*az; zz += az*az;
    }
    double* msd = &mstats[(blockIdx.x & (MCOPY-1))*27];
#define RED27(v, i) { float r_ = (v); \
    r_ += __shfl_xor(r_, 1);  r_ += __shfl_xor(r_, 2);  r_ += __shfl_xor(r_, 4); \
    r_ += __shfl_xor(r_, 8);  r_ += __shfl_xor(r_, 16); r_ += __shfl_xor(r_, 32); \
    if (lane == 0) atomicAdd(&msd[i], (double)r_); }
    RED27(nx, 0) RED27(ny, 1) RED27(nz, 2)
    RED27(qx, 3) RED27(qy, 4) RED27(qz, 5)
    RED27(xx, 6) RED27(xy, 7) RED27(xz, 8)
    RED27(yy, 9) RED27(yz, 10) RED27(zz, 11)
    RED27(nx*qx, 12) RED27(nx*qy, 13) RED27(nx*qz, 14)
    RED27(ny*qx, 15) RED27(ny*qy, 16) RED27(ny*qz, 17)
    RED27(nz*qx, 18) RED27(nz*qy, 19) RED27(nz*qz, 20)
    RED27(qx*qx, 21) RED27(qx*qy, 22) RED27(qx*qz, 23)
    RED27(qy*qy, 24) RED27(qy*qz, 25) RED27(qz*qz, 26)
#undef RED27
}

/* split fp32 -> bf16 hi (truncate) + bf16 lo (truncated remainder) */
__device__ __forceinline__ void bsplit(float g, short& hi, short& lo) {
    unsigned bits = __float_as_uint(g);
    unsigned hbits = bits & 0xFFFF0000u;
    float rem = g - __uint_as_float(hbits);
    hi = (short)(bits >> 16);
    lo = (short)(__float_as_uint(rem) >> 16);
}

/* ---------------- K5: main pass — shared-leftover-tile split-bf16 MFMA --------- */
__global__ __launch_bounds__(256) void main_kernel(const int* __restrict__ idxb,
        const int* __restrict__ rankArr, const float4* __restrict__ pts4,
        const double* __restrict__ ms, const float* __restrict__ W1,
        const float* __restrict__ gamma1, const float* __restrict__ beta1,
        const float* __restrict__ W2,
        float* __restrict__ maxbuf, float* __restrict__ stats2f) {
    __shared__ __align__(16) short Thi[4][32*72];
    __shared__ __align__(16) short Tlo[4][32*72];
    __shared__ float chs[128];
    __shared__ float ab1s[128];
    __shared__ double msd[27];
    const int tid = threadIdx.x;
    const int lane = tid & 63;
    const int wv = __builtin_amdgcn_readfirstlane(tid >> 6);
    const int l15 = lane & 15;
    const int quad = lane >> 4;
    if (tid < 128) chs[tid] = 0.f;
    if (tid < 27) {                                /* sum the 32 mstats copies */
        double t = 0.0;
        for (int c = 0; c < MCOPY; ++c) t += ms[c*27 + tid];
        msd[tid] = t;
    }
    __syncthreads();
    if (tid < 64) {                                /* inline fin1m (bn1 affine) */
        int c = tid;
        double wu[3], wvv[3];
#pragma unroll
        for (int i = 0; i < 3; ++i) {
            wu[i] = (double)W1[c*6 + i];
            wvv[i] = (double)W1[c*6 + 3 + i] - wu[i];
        }
        const double S = (double)SAMPLES;
        double mean = (wu[0]*msd[0] + wu[1]*msd[1] + wu[2]*msd[2]
                     + 20.0*(wvv[0]*msd[3] + wvv[1]*msd[4] + wvv[2]*msd[5])) / S;
        double qM1 = wu[0]*wu[0]*msd[6] + wu[1]*wu[1]*msd[9] + wu[2]*wu[2]*msd[11]
                   + 2.0*(wu[0]*wu[1]*msd[7] + wu[0]*wu[2]*msd[8] + wu[1]*wu[2]*msd[10]);
        double cross = 0.0;
#pragma unroll
        for (int i = 0; i < 3; ++i)
#pragma unroll
            for (int j = 0; j < 3; ++j)
                cross += wu[i] * msd[12 + i*3 + j] * wvv[j];
        double qpp = wvv[0]*wvv[0]*msd[21] + wvv[1]*wvv[1]*msd[24] + wvv[2]*wvv[2]*msd[26]
                   + 2.0*(wvv[0]*wvv[1]*msd[22] + wvv[0]*wvv[2]*msd[23] + wvv[1]*wvv[2]*msd[25]);
        double e2 = (qM1 + 2.0*cross + 20.0*qpp) / S;
        double var = e2 - mean*mean;
        float a = (float)((double)gamma1[c] / sqrt(var + (double)EPSF));
        ab1s[c] = a;
        ab1s[64 + c] = beta1[c] - a * (float)mean;
    }
    __syncthreads();

    bf16x8 whi[8], wlo[8];
#pragma unroll
    for (int t = 0; t < 4; ++t)
#pragma unroll
    for (int f = 0; f < 2; ++f) {
        const int o = 16*t + l15;
        const int c0 = 32*f + quad*8;
        const float4* wr = (const float4*)(W2 + o*64 + c0);
        float4 w0 = wr[0], w1 = wr[1];
        float vals[8] = {w0.x,w0.y,w0.z,w0.w,w1.x,w1.y,w1.z,w1.w};
        bf16x8 h, l;
#pragma unroll
        for (int j = 0; j < 8; ++j) { short hj, lj; bsplit(vals[j], hj, lj); h[j]=hj; l[j]=lj; }
        whi[t*2+f] = h; wlo[t*2+f] = l;
    }

    const float w10 = W1[lane*6+0], w11 = W1[lane*6+1], w12 = W1[lane*6+2];
    const float w13 = W1[lane*6+3], w14 = W1[lane*6+4], w15 = W1[lane*6+5];
    const float a1 = ab1s[lane], b1 = ab1s[64 + lane];
    float ssum[4] = {0.f,0.f,0.f,0.f}, ssq[4] = {0.f,0.f,0.f,0.f};
    float lm[4][4];                                /* deferred tile1 max [point][t] */
    short* thi = &Thi[wv][0];
    short* tlo = &Tlo[wv][0];

    const int pt0 = (blockIdx.x * 4 + wv) * 4;
    const int b = pt0 >> 12;
    const float4* pb = pts4 + ((size_t)b << 12);
    const int* rnk = rankArr + ((size_t)b << 12);

    for (int p = 0; p < 4; ++p) {
        const int pt = pt0 + p;
        const float4 pc = pb[pt & (NN - 1)];
        const float X = -0.5f*pc.x, Y = -0.5f*pc.y, Z = -0.5f*pc.z;
        const float vc = (w13 - w10)*X + (w14 - w11)*Y + (w15 - w12)*Z;
        const int srow = rnk[pt & (NN - 1)];       /* uniform scalar lookup */
        const int* irow = idxb + ((size_t)((b << 12) + srow)) * KNN;
#pragma unroll
        for (int k = 0; k < KNN; ++k) {
            float4 pn = pb[irow[k]];
            float nx = -0.5f*pn.x, ny = -0.5f*pn.y, nz = -0.5f*pn.z;
            float uc = w10*nx + w11*ny + w12*nz;
            float g = a1 * (uc + vc) + b1;
            g = fmaxf(g, SLOPE * g);
            short hj, lj; bsplit(g, hj, lj);
            const int row = (k < 16) ? k : (16 + p*4 + (k - 16));
            thi[row*72 + lane] = hj;
            tlo[row*72 + lane] = lj;
        }
        __builtin_amdgcn_wave_barrier();

        bf16x8 ah1[2], al1[2];
#pragma unroll
        for (int f = 0; f < 2; ++f) {
            const int co = 32*f + quad*8;
            ah1[f] = *(const bf16x8*)&thi[l15*72 + co];
            al1[f] = *(const bf16x8*)&tlo[l15*72 + co];
        }

        f32x4 acc1[4];
#pragma unroll
        for (int t = 0; t < 4; ++t) acc1[t] = (f32x4)0.f;
#pragma unroll
        for (int t = 0; t < 4; ++t) {
#pragma unroll
            for (int f = 0; f < 2; ++f) {
                acc1[t] = __builtin_amdgcn_mfma_f32_16x16x32_bf16(ah1[f], whi[t*2+f], acc1[t], 0,0,0);
                acc1[t] = __builtin_amdgcn_mfma_f32_16x16x32_bf16(al1[f], whi[t*2+f], acc1[t], 0,0,0);
                acc1[t] = __builtin_amdgcn_mfma_f32_16x16x32_bf16(ah1[f], wlo[t*2+f], acc1[t], 0,0,0);
            }
        }
        __builtin_amdgcn_wave_barrier();           /* tile1 reads done before next p */

        /* tile1 epilogue: reduce over rows k=0..15 (quads), defer the write */
#pragma unroll
        for (int t = 0; t < 4; ++t) {
            float m1 = fmaxf(fmaxf(acc1[t][0], acc1[t][1]), fmaxf(acc1[t][2], acc1[t][3]));
            float s1 = acc1[t][0] + acc1[t][1] + acc1[t][2] + acc1[t][3];
            float q1 = acc1[t][0]*acc1[t][0] + acc1[t][1]*acc1[t][1]
                     + acc1[t][2]*acc1[t][2] + acc1[t][3]*acc1[t][3];
            m1 = fmaxf(m1, __shfl_xor(m1, 16)); m1 = fmaxf(m1, __shfl_xor(m1, 32));
            s1 += __shfl_xor(s1, 16); s1 += __shfl_xor(s1, 32);
            q1 += __shfl_xor(q1, 16); q1 += __shfl_xor(q1, 32);
            lm[p][t] = m1;
            ssum[t] += s1; ssq[t] += q1;
        }
    }

    /* combined leftover tile: rows = p*4+(k-16), read once, 24 MFMA */
    {
        bf16x8 ah2[2], al2[2];
#pragma unroll
        for (int f = 0; f < 2; ++f) {
            const int co = 32*f + quad*8;
            ah2[f] = *(const bf16x8*)&thi[(16 + l15)*72 + co];
            al2[f] = *(const bf16x8*)&tlo[(16 + l15)*72 + co];
        }
        f32x4 accC[4];
#pragma unroll
        for (int t = 0; t < 4; ++t) accC[t] = (f32x4)0.f;
#pragma unroll
        for (int t = 0; t < 4; ++t) {
#pragma unroll
            for (int f = 0; f < 2; ++f) {
                accC[t] = __builtin_amdgcn_mfma_f32_16x16x32_bf16(ah2[f], whi[t*2+f], accC[t], 0,0,0);
                accC[t] = __builtin_amdgcn_mfma_f32_16x16x32_bf16(al2[f], whi[t*2+f], accC[t], 0,0,0);
                accC[t] = __builtin_amdgcn_mfma_f32_16x16x32_bf16(ah2[f], wlo[t*2+f], accC[t], 0,0,0);
            }
        }
        /* C row = quad*4+reg -> point = quad, k = 16+reg. */
#pragma unroll
        for (int t = 0; t < 4; ++t) {
            float cm = fmaxf(fmaxf(accC[t][0], accC[t][1]), fmaxf(accC[t][2], accC[t][3]));
            float cs = accC[t][0] + accC[t][1] + accC[t][2] + accC[t][3];
            float cq = accC[t][0]*accC[t][0] + accC[t][1]*accC[t][1]
                     + accC[t][2]*accC[t][2] + accC[t][3]*accC[t][3];
            float lmq = (quad == 0) ? lm[0][t] : (quad == 1) ? lm[1][t]
                      : (quad == 2) ? lm[2][t] : lm[3][t];
            maxbuf[((size_t)(pt0 + quad) << 6) + 16*t + l15] = fmaxf(lmq, cm);
            cs += __shfl_xor(cs, 16); cs += __shfl_xor(cs, 32);
            cq += __shfl_xor(cq, 16); cq += __shfl_xor(cq, 32);
            ssum[t] += cs; ssq[t] += cq;
        }
    }

    if (quad == 0) {
#pragma unroll
        for (int t = 0; t < 4; ++t) {
            atomicAdd(&chs[16*t + l15], ssum[t]);
            atomicAdd(&chs[64 + 16*t + l15], ssq[t]);
        }
    }
    __syncthreads();
    if (tid < 128)
        atomicAdd(&stats2f[(blockIdx.x & 1)*128 + tid], chs[tid]);
}

/* ---------------- K7: epilogue — fin2 inlined; transpose + bn2 + lrelu --------- */
__global__ __launch_bounds__(256) void out_kernel(const float* __restrict__ maxbuf,
        const float* __restrict__ s2f, const float* __restrict__ gamma2,
        const float* __restrict__ beta2, float* __restrict__ out) {
    __shared__ float t[64][65];
    __shared__ float ab2s[128];
    const int tid = threadIdx.x;
    if (tid < 64) {                                /* inline fin2 */
        int o = tid;
        double sum = (double)s2f[o] + (double)s2f[128 + o];
        double sq  = (double)s2f[64 + o] + (double)s2f[192 + o];
        double cnt = (double)SAMPLES;
        double mean = sum / cnt;
        double var  = sq / cnt - mean*mean;
        float a = (float)((double)gamma2[o] / sqrt(var + (double)EPSF));
        ab2s[o] = a;
        ab2s[64 + o] = beta2[o] - a * (float)mean;
    }
    const int b = blockIdx.x >> 6;
    const int n0 = (blockIdx.x & 63) << 6;
#pragma unroll
    for (int i = 0; i < 16; ++i) {
        int r = (tid >> 6) + i*4;
        int c = tid & 63;
        t[r][c] = maxbuf[(((size_t)((b << 12) + n0 + r)) << 6) + c];
    }
    __syncthreads();
#pragma unroll
    for (int i = 0; i < 16; ++i) {
        int o = (tid >> 6) + i*4;
        int nn = tid & 63;
        float a = ab2s[o], bb = ab2s[64 + o];
        float h = a * t[nn][o] + bb;
        out[(((size_t)(b*64 + o)) << 12) + n0 + nn] = h >= 0.f ? h : SLOPE*h;
    }
}

extern "C" void kernel_launch(void* const* d_in, const int* in_sizes, int n_in,
                              void* d_out, int out_size, void* d_ws, size_t ws_size,
                              hipStream_t stream) {
    const float* x      = (const float*)d_in[0];
    const float* W1     = (const float*)d_in[1];
    const float* gamma1 = (const float*)d_in[2];
    const float* beta1  = (const float*)d_in[3];
    const float* W2     = (const float*)d_in[4];
    const float* gamma2 = (const float*)d_in[5];
    const float* beta2  = (const float*)d_in[6];
    float* out = (float*)d_out;

    char* ws = (char*)d_ws;
    int*    idxb    = (int*)   (ws + 0);           /* 2,621,440 B (sorted order) */
    float4* pts4    = (float4*)(ws + 2621440);     /* 512 KB */
    float4* sp4     = (float4*)(ws + 3145728);     /* 512 KB sorted pts */
    int*    sidx    = (int*)   (ws + 3670016);     /* 128 KB sorted->orig */
    int*    rankArr = (int*)   (ws + 3801088);     /* 128 KB orig->sorted */
    float*  maxbuf  = (float*) (ws + 19398656);    /* 8,388,608 B, (b,n,o) */
    double* mstats  = (double*)(ws + 27787264);    /* 32x27 doubles = 6912 B */
    float*  stats2f = (float*) (ws + 27794176);    /* 2x128 floats = 1024 B */
    double* zreg    = (double*)(ws + 27787264);    /* zero region: 992 doubles */

    sort_kernel <<<8, 1024, 0, stream>>>(x, pts4, sp4, sidx, rankArr, zreg);
    knn_kernel  <<<512, 64, 0, stream>>>(pts4, sp4, sidx, idxb, mstats);
    main_kernel <<<2048, 256, 0, stream>>>(idxb, rankArr, pts4, mstats, W1, gamma1,
                                           beta1, W2, maxbuf, stats2f);
    out_kernel  <<<512, 256, 0, stream>>>(maxbuf, stats2f, gamma2, beta2, out);
}